// Round 1
// baseline (217.583 us; speedup 1.0000x reference)
//
#include <hip/hip_runtime.h>
#include <stdint.h>

#define DIM   128
#define MN    1024
#define BATCH 2048
#define ALPHA 0.3f
#define NITERF 100.0f
#define SIGMA 16.0f

// ---------------------------------------------------------------------------
// Kernel 1: BMU search.
// grid = 256 blocks (16 u-tiles x 16 b-tiles), 256 threads.
// Block tile: 64 units x 128 batch, K=128 dims in 4 LDS tiles of 32.
// Thread tile: 4u x 8b. Score s = w2 - 2*dot (x2 constant per b, drops out).
// Key = (orderable_bits(s) << 32) | u  -> atomicMin gives first-min-index
// semantics like jnp.argmin.
// ---------------------------------------------------------------------------
__global__ __launch_bounds__(256) void bmu_kernel(
    const float* __restrict__ x, const float* __restrict__ w,
    unsigned long long* __restrict__ keys)
{
  // +4 pad keeps 16B alignment for b128 reads; row stride 36 floats gives
  // 2-way-or-free bank aliasing for the interleaved (stride-16) row access.
  __shared__ __align__(16) float wt[64][36];
  __shared__ __align__(16) float xt[128][36];
  __shared__ unsigned long long bkey[128];

  const int t  = threadIdx.x;
  const int tu = t & 15;    // unit-thread: units tu + 16*i
  const int tb = t >> 4;    // batch-thread: batches tb + 16*j
  const int u0 = (blockIdx.x & 15) * 64;
  const int b0 = (blockIdx.x >> 4) * 128;

  if (t < 128) bkey[t] = ~0ull;

  float acc[4][8];
  float w2[4];
#pragma unroll
  for (int i = 0; i < 4; ++i) {
    w2[i] = 0.f;
#pragma unroll
    for (int j = 0; j < 8; ++j) acc[i][j] = 0.f;
  }

  for (int kt = 0; kt < 4; ++kt) {
    const int k0 = kt * 32;
    __syncthreads();
    // stage w tile: 64 x 32 floats = 512 float4, 2 per thread (coalesced)
#pragma unroll
    for (int r = 0; r < 2; ++r) {
      int idx = t + 256 * r;
      int uu = idx >> 3, kq = idx & 7;
      float4 v = *reinterpret_cast<const float4*>(&w[(u0 + uu) * DIM + k0 + kq * 4]);
      *reinterpret_cast<float4*>(&wt[uu][kq * 4]) = v;
    }
    // stage x tile: 128 x 32 floats = 1024 float4, 4 per thread
#pragma unroll
    for (int r = 0; r < 4; ++r) {
      int idx = t + 256 * r;
      int bb = idx >> 3, kq = idx & 7;
      float4 v = *reinterpret_cast<const float4*>(&x[(b0 + bb) * DIM + k0 + kq * 4]);
      *reinterpret_cast<float4*>(&xt[bb][kq * 4]) = v;
    }
    __syncthreads();
#pragma unroll
    for (int kq = 0; kq < 8; ++kq) {
      float4 aq[4], bq[8];
#pragma unroll
      for (int i = 0; i < 4; ++i)
        aq[i] = *reinterpret_cast<const float4*>(&wt[tu + 16 * i][kq * 4]);
#pragma unroll
      for (int j = 0; j < 8; ++j)
        bq[j] = *reinterpret_cast<const float4*>(&xt[tb + 16 * j][kq * 4]);
#pragma unroll
      for (int i = 0; i < 4; ++i) {
        w2[i] += aq[i].x * aq[i].x + aq[i].y * aq[i].y +
                 aq[i].z * aq[i].z + aq[i].w * aq[i].w;
#pragma unroll
        for (int j = 0; j < 8; ++j) {
          acc[i][j] += aq[i].x * bq[j].x + aq[i].y * bq[j].y +
                       aq[i].z * bq[j].z + aq[i].w * bq[j].w;
        }
      }
    }
  }

  // per-thread min over 4 units, then LDS atomicMin, then global atomicMin
#pragma unroll
  for (int j = 0; j < 8; ++j) {
    unsigned long long kmin = ~0ull;
#pragma unroll
    for (int i = 0; i < 4; ++i) {
      float s = w2[i] - 2.f * acc[i][j];
      unsigned int bb = __float_as_uint(s);
      bb ^= (bb >> 31) ? 0xFFFFFFFFu : 0x80000000u;  // total order as unsigned
      unsigned long long key =
          ((unsigned long long)bb << 32) | (unsigned int)(u0 + tu + 16 * i);
      kmin = key < kmin ? key : kmin;
    }
    atomicMin(&bkey[tb + 16 * j], kmin);
  }
  __syncthreads();
  if (tu == 0) {
#pragma unroll
    for (int j = 0; j < 8; ++j) {
      int lb = tb + 16 * j;
      atomicMin(&keys[b0 + lb], bkey[lb]);
    }
  }
}

// ---------------------------------------------------------------------------
// Kernel 2: lr_op GEMM + rowsum, split-K over batch.
// grid = 256 blocks (8 u-tiles x 32 batch-chunks of 64), 256 threads.
// Block tile: 128u x 128d, K-chunk = 64 b in 2 LDS tiles of 32.
// Thread tile: 8u x 8d. lr computed in-kernel (one exp per (u,b) pair).
// Partials accumulated into ws via native fp32 atomics.
// ---------------------------------------------------------------------------
__global__ __launch_bounds__(256) void update_kernel(
    const float* __restrict__ x, const int* __restrict__ loc,
    const unsigned long long* __restrict__ keys,
    const int* __restrict__ itp,
    float* __restrict__ gacc, float* __restrict__ growsum)
{
  __shared__ __align__(16) float lrt[128][36];  // [u][b]
  __shared__ __align__(16) float xtt[128][36];  // x^T: [d][b]
  __shared__ float blx[32], bly[32];

  const int t  = threadIdx.x;
  const int tu = t & 15;   // units tu + 16*i
  const int td = t >> 4;   // dims td*4 + j (two quads)
  const int u0    = (blockIdx.x >> 5) * 128;
  const int bbase = (blockIdx.x & 31) * 64;

  const float lr_decay = 1.0f - (float)itp[0] / NITERF;
  const float alpha_op = ALPHA * lr_decay;
  const float sg       = SIGMA * lr_decay;
  const float ninv_s2  = -1.0f / (sg * sg);

  // lr-staging assignment: this thread fills row uw for 16 b's
  const int uw   = t & 127;
  const int half = t >> 7;
  const float ulx = (float)loc[2 * (u0 + uw)];
  const float uly = (float)loc[2 * (u0 + uw) + 1];

  int dj[8];
#pragma unroll
  for (int j = 0; j < 4; ++j) { dj[j] = td * 4 + j; dj[j + 4] = 64 + td * 4 + j; }

  float facc[8][8];
  float rs[8];
#pragma unroll
  for (int i = 0; i < 8; ++i) {
    rs[i] = 0.f;
#pragma unroll
    for (int j = 0; j < 8; ++j) facc[i][j] = 0.f;
  }

  for (int bt = 0; bt < 2; ++bt) {
    const int b0 = bbase + bt * 32;
    __syncthreads();  // protect prev iteration's LDS reads
    if (t < 32) {
      unsigned long long k = keys[b0 + t];
      unsigned int u = (unsigned int)(k & 0xFFFFFFFFull);
      blx[t] = (float)loc[2 * u];
      bly[t] = (float)loc[2 * u + 1];
    }
    // stage x^T: 32 b x 128 d, coalesced float4 reads, scalar LDS writes
#pragma unroll
    for (int r = 0; r < 4; ++r) {
      int idx = t + 256 * r;
      int bl = idx >> 5, dq = idx & 31;
      float4 v = *reinterpret_cast<const float4*>(&x[(b0 + bl) * DIM + dq * 4]);
      xtt[dq * 4 + 0][bl] = v.x;
      xtt[dq * 4 + 1][bl] = v.y;
      xtt[dq * 4 + 2][bl] = v.z;
      xtt[dq * 4 + 3][bl] = v.w;
    }
    __syncthreads();  // blx/bly visible
#pragma unroll
    for (int s = 0; s < 16; ++s) {
      int bl = half * 16 + s;
      float dx = ulx - blx[bl], dy = uly - bly[bl];
      lrt[uw][bl] = alpha_op * __expf((dx * dx + dy * dy) * ninv_s2);
    }
    __syncthreads();  // lrt visible
#pragma unroll
    for (int bq = 0; bq < 8; ++bq) {
      float4 lq[8], xq[8];
#pragma unroll
      for (int i = 0; i < 8; ++i)
        lq[i] = *reinterpret_cast<const float4*>(&lrt[tu + 16 * i][bq * 4]);
#pragma unroll
      for (int j = 0; j < 8; ++j)
        xq[j] = *reinterpret_cast<const float4*>(&xtt[dj[j]][bq * 4]);
#pragma unroll
      for (int i = 0; i < 8; ++i) {
        rs[i] += lq[i].x + lq[i].y + lq[i].z + lq[i].w;
#pragma unroll
        for (int j = 0; j < 8; ++j) {
          facc[i][j] += lq[i].x * xq[j].x + lq[i].y * xq[j].y +
                        lq[i].z * xq[j].z + lq[i].w * xq[j].w;
        }
      }
    }
  }

  // epilogue: atomically accumulate partials
#pragma unroll
  for (int i = 0; i < 8; ++i) {
    const int u = u0 + tu + 16 * i;
#pragma unroll
    for (int j = 0; j < 8; ++j)
      unsafeAtomicAdd(&gacc[u * DIM + dj[j]], facc[i][j]);
  }
  if (td == 0) {
#pragma unroll
    for (int i = 0; i < 8; ++i)
      unsafeAtomicAdd(&growsum[u0 + tu + 16 * i], rs[i]);
  }
}

// ---------------------------------------------------------------------------
// Kernel 3: out = w*(1 - rowsum[u]) + acc   (float4, 128 blocks x 256 thr)
// ---------------------------------------------------------------------------
__global__ __launch_bounds__(256) void finalize_kernel(
    const float* __restrict__ w, const float* __restrict__ gacc,
    const float* __restrict__ growsum, float* __restrict__ out)
{
  int q = blockIdx.x * 256 + threadIdx.x;  // quad index, 32768 total
  int u = q >> 5;                          // q*4 / 128
  float rsv = growsum[u];
  float4 wq = *reinterpret_cast<const float4*>(&w[q * 4]);
  float4 aq = *reinterpret_cast<const float4*>(&gacc[q * 4]);
  float4 o;
  o.x = wq.x * (1.f - rsv) + aq.x;
  o.y = wq.y * (1.f - rsv) + aq.y;
  o.z = wq.z * (1.f - rsv) + aq.z;
  o.w = wq.w * (1.f - rsv) + aq.w;
  *reinterpret_cast<float4*>(&out[q * 4]) = o;
}

extern "C" void kernel_launch(void* const* d_in, const int* in_sizes, int n_in,
                              void* d_out, int out_size, void* d_ws, size_t ws_size,
                              hipStream_t stream) {
  const float* x   = (const float*)d_in[0];   // [2048,128] f32
  const float* w   = (const float*)d_in[1];   // [1024,128] f32
  const int*   loc = (const int*)d_in[2];     // [1024,2] i32
  const int*   itp = (const int*)d_in[3];     // [1] i32
  float* out = (float*)d_out;                 // [1024,128] f32

  // workspace layout
  unsigned long long* keys = (unsigned long long*)d_ws;        // 2048*8  = 16 KB
  float* gacc    = (float*)((char*)d_ws + 16384);              // 1024*128*4 = 512 KB
  float* growsum = (float*)((char*)d_ws + 16384 + 524288);     // 1024*4 = 4 KB

  hipMemsetAsync(d_ws, 0xFF, 16384, stream);                    // keys = +inf
  hipMemsetAsync((char*)d_ws + 16384, 0, 524288 + 4096, stream);// acc/rowsum = 0

  bmu_kernel<<<256, 256, 0, stream>>>(x, w, keys);
  update_kernel<<<256, 256, 0, stream>>>(x, loc, keys, itp, gacc, growsum);
  finalize_kernel<<<128, 256, 0, stream>>>(w, gacc, growsum, out);
}